// Round 5
// baseline (2975.505 us; speedup 1.0000x reference)
//
#include <hip/hip_runtime.h>
#include <hip/hip_bf16.h>

#define BM 128
#define BN 128
#define BK 32
#define LDSS 40   // LDS leading stride (elements): 80B rows, 16B-multiple, breaks pow2 banks

typedef short short8 __attribute__((ext_vector_type(8)));
typedef float f32x4 __attribute__((ext_vector_type(4)));

using bf = __hip_bfloat16;

union U4 { uint4 u; ushort s[8]; };

// ---------------------------------------------------------------------------
// Runtime dtype detection (kept as a guard; selected fp32 in round 4).
// Genuine bf16 here has biased exp <= ~0x82; fp32 low-halves are random:
// P(exp-field >= 0xC0) = 1/4 per word -> certainty 1-(3/4)^128.
// ---------------------------------------------------------------------------
__device__ __forceinline__ bool src_is_f32(const void* src)
{
    const ushort* us = (const ushort*)src;
    int lane = threadIdx.x & 63;
    ushort4 p = *(const ushort4*)(us + lane * 4);
    int hit = (((p.x >> 7) & 0xFF) >= 0xC0) | (((p.y >> 7) & 0xFF) >= 0xC0) |
              (((p.z >> 7) & 0xFF) >= 0xC0) | (((p.w >> 7) & 0xFF) >= 0xC0);
    return __any(hit);
}

__global__ __launch_bounds__(256)
void to_bf16(const void* __restrict__ src, bf* __restrict__ dst, int n)
{
    bool f32 = src_is_f32(src);
    int i = (blockIdx.x * 256 + threadIdx.x) * 4;
    if (i >= n) return;
    if (f32) {
        float4 v = *(const float4*)((const float*)src + i);
        bf o[4];
        o[0] = __float2bfloat16(v.x);
        o[1] = __float2bfloat16(v.y);
        o[2] = __float2bfloat16(v.z);
        o[3] = __float2bfloat16(v.w);
        *(uint2*)(dst + i) = *(const uint2*)o;
    } else {
        *(uint2*)(dst + i) = *(const uint2*)((const ushort*)src + i);
    }
}

__global__ __launch_bounds__(256)
void to_f32(const void* __restrict__ src, float* __restrict__ dst, int n)
{
    bool f32 = src_is_f32(src);
    for (int i = blockIdx.x * 256 + threadIdx.x; i < n; i += gridDim.x * 256)
        dst[i] = f32 ? ((const float*)src)[i]
                     : __bfloat162float(((const bf*)src)[i]);
}

// ---------------------------------------------------------------------------
// C = A[M,K] @ W[K,N] + bias(fp32); A/W bf16, fp32 accumulate, C dtype = CT.
// Split-A: k < splitA reads A, else A2 at k-splitA (same lda).
// ---------------------------------------------------------------------------
template <typename CT>
__global__ __launch_bounds__(256)
void gemm_nn(const bf* __restrict__ A, const bf* __restrict__ A2, int splitA,
             const bf* __restrict__ W, const float* __restrict__ bias,
             CT* __restrict__ C, int K, int lda, int ldw, int ldc)
{
    __shared__ __align__(16) ushort sA[BM * LDSS];
    __shared__ __align__(16) ushort sB[BN * LDSS];

    const int t = threadIdx.x;
    const int m0 = blockIdx.x * BM;
    const int n0 = blockIdx.y * BN;

    const int wave = t >> 6;
    const int lane = t & 63;
    const int wm = wave >> 1, wn = wave & 1;
    const int lcol = lane & 15, quad = lane >> 4;

    f32x4 acc[4][4] = {};

    for (int kt = 0; kt < K; kt += BK) {
        const bf* Asrc = (kt < splitA) ? A : A2;
        const int ktt = (kt < splitA) ? kt : kt - splitA;
        #pragma unroll
        for (int it = 0; it < 2; ++it) {
            int idx = t + it * 256;
            int m = idx >> 2;
            int kg = (idx & 3) << 3;
            *(uint4*)&sA[m * LDSS + kg] =
                *(const uint4*)(Asrc + (size_t)(m0 + m) * lda + ktt + kg);
        }
        #pragma unroll
        for (int it = 0; it < 2; ++it) {
            int idx = t + it * 256;
            int k = idx >> 4;
            int ng = (idx & 15) << 3;
            U4 v;
            v.u = *(const uint4*)(W + (size_t)(kt + k) * ldw + n0 + ng);
            #pragma unroll
            for (int j = 0; j < 8; ++j) sB[(ng + j) * LDSS + k] = v.s[j];
        }
        __syncthreads();

        short8 af[4], bfr[4];
        #pragma unroll
        for (int i = 0; i < 4; ++i)
            af[i] = *(const short8*)&sA[(wm * 64 + i * 16 + lcol) * LDSS + quad * 8];
        #pragma unroll
        for (int j = 0; j < 4; ++j)
            bfr[j] = *(const short8*)&sB[(wn * 64 + j * 16 + lcol) * LDSS + quad * 8];
        #pragma unroll
        for (int i = 0; i < 4; ++i)
            #pragma unroll
            for (int j = 0; j < 4; ++j)
                acc[i][j] = __builtin_amdgcn_mfma_f32_16x16x32_bf16(af[i], bfr[j], acc[i][j], 0, 0, 0);
        __syncthreads();
    }

    #pragma unroll
    for (int j = 0; j < 4; ++j) {
        int col = n0 + wn * 64 + j * 16 + lcol;
        float bv = bias ? bias[col] : 0.0f;
        #pragma unroll
        for (int i = 0; i < 4; ++i) {
            int row = m0 + wm * 64 + i * 16 + quad * 4;
            #pragma unroll
            for (int r = 0; r < 4; ++r) {
                float v = acc[i][j][r] + bv;
                C[(size_t)(row + r) * ldc + col] = (CT)v;   // bf: converting ctor; float: identity
            }
        }
    }
}

// ---------------------------------------------------------------------------
// E[q,k] = exp((Q[q,:] . Km[k,:]) * rscale) + column sums over q
// (softmax is over the QUERY axis). Per batch element. Grid (S/BM, S/BN).
// ---------------------------------------------------------------------------
__global__ __launch_bounds__(256)
void scores_exp(const bf* __restrict__ Q, const bf* __restrict__ Km,
                bf* __restrict__ E, float* __restrict__ colsum,
                int Dd, int Ss, float rscale)
{
    __shared__ __align__(16) ushort sA[BM * LDSS];
    __shared__ __align__(16) ushort sB[BN * LDSS];

    const int t = threadIdx.x;
    const int m0 = blockIdx.x * BM;
    const int n0 = blockIdx.y * BN;

    const int wave = t >> 6;
    const int lane = t & 63;
    const int wm = wave >> 1, wn = wave & 1;
    const int lcol = lane & 15, quad = lane >> 4;

    f32x4 acc[4][4] = {};

    for (int kt = 0; kt < Dd; kt += BK) {
        #pragma unroll
        for (int it = 0; it < 2; ++it) {
            int idx = t + it * 256;
            int m = idx >> 2;
            int kg = (idx & 3) << 3;
            *(uint4*)&sA[m * LDSS + kg] =
                *(const uint4*)(Q + (size_t)(m0 + m) * Dd + kt + kg);
        }
        #pragma unroll
        for (int it = 0; it < 2; ++it) {
            int idx = t + it * 256;
            int n = idx >> 2;
            int kg = (idx & 3) << 3;
            *(uint4*)&sB[n * LDSS + kg] =
                *(const uint4*)(Km + (size_t)(n0 + n) * Dd + kt + kg);
        }
        __syncthreads();

        short8 af[4], bfr[4];
        #pragma unroll
        for (int i = 0; i < 4; ++i)
            af[i] = *(const short8*)&sA[(wm * 64 + i * 16 + lcol) * LDSS + quad * 8];
        #pragma unroll
        for (int j = 0; j < 4; ++j)
            bfr[j] = *(const short8*)&sB[(wn * 64 + j * 16 + lcol) * LDSS + quad * 8];
        #pragma unroll
        for (int i = 0; i < 4; ++i)
            #pragma unroll
            for (int j = 0; j < 4; ++j)
                acc[i][j] = __builtin_amdgcn_mfma_f32_16x16x32_bf16(af[i], bfr[j], acc[i][j], 0, 0, 0);
        __syncthreads();
    }

    float csum[4] = {0.f, 0.f, 0.f, 0.f};
    #pragma unroll
    for (int j = 0; j < 4; ++j) {
        int col = n0 + wn * 64 + j * 16 + lcol;
        #pragma unroll
        for (int i = 0; i < 4; ++i) {
            int row = m0 + wm * 64 + i * 16 + quad * 4;
            #pragma unroll
            for (int r = 0; r < 4; ++r) {
                float e = __expf(acc[i][j][r] * rscale);
                E[(size_t)(row + r) * Ss + col] = __float2bfloat16(e);
                csum[j] += e;
            }
        }
    }
    #pragma unroll
    for (int j = 0; j < 4; ++j) {
        float v = csum[j];
        v += __shfl_xor(v, 16);
        v += __shfl_xor(v, 32);
        if (quad == 0) {
            int col = n0 + wn * 64 + j * 16 + lcol;
            atomicAdd(&colsum[col], v);
        }
    }
}

__global__ __launch_bounds__(256)
void scale_rows(bf* __restrict__ V, const float* __restrict__ colsum, int Dd)
{
    size_t row = blockIdx.x;
    float r = 1.0f / colsum[row];
    bf* p = V + row * Dd;
    for (int d = threadIdx.x; d < Dd; d += 256)
        p[d] = __float2bfloat16(__bfloat162float(p[d]) * r);
}

// gating: F1 = a2*self + (1-a2)*conv ; F2 = a1*conv + (1-a1)*self
__global__ __launch_bounds__(256)
void gate_fuse(const bf* __restrict__ O1, const bf* __restrict__ O2,
               const bf* __restrict__ SX, const bf* __restrict__ CX,
               bf* __restrict__ F1, bf* __restrict__ F2, int Dd)
{
    size_t base = (size_t)blockIdx.x * Dd;
    for (int d = threadIdx.x; d < Dd; d += 256) {
        float o1 = __bfloat162float(O1[base + d]);
        float o2 = __bfloat162float(O2[base + d]);
        float sx = __bfloat162float(SX[base + d]);
        float cx = __bfloat162float(CX[base + d]);
        float a1 = 1.0f / (1.0f + __expf(-tanhf(o1)));
        float a2 = 1.0f / (1.0f + __expf(-tanhf(o2)));
        F1[base + d] = __float2bfloat16(a2 * sx + (1.0f - a2) * cx);
        F2[base + d] = __float2bfloat16(a1 * cx + (1.0f - a1) * sx);
    }
}

extern "C" void kernel_launch(void* const* d_in, const int* in_sizes, int n_in,
                              void* d_out, int out_size, void* d_ws, size_t ws_size,
                              hipStream_t stream)
{
    const int B = 8, S = 2048, D = 768;
    const int M = B * S;                       // 16384
    const int NOSPLIT = 1 << 30;

    const void* Wsrc[7] = { d_in[2], d_in[4], d_in[6], d_in[8], d_in[10], d_in[12], d_in[14] };
    const void* bsrc[7] = { d_in[3], d_in[5], d_in[7], d_in[9], d_in[11], d_in[13], d_in[15] };
    float* out = (float*)d_out;   // reference output dtype = float32

    // ---- workspace layout (169 MB, round-3/4 proven-safe footprint) ----
    char* w = (char*)d_ws;
    const size_t MD  = (size_t)M * D * sizeof(bf);      // 25.17 MB
    const size_t WSZ = (size_t)D * D * sizeof(bf);      // 1.18 MB
    bf* Xs = (bf*)(w);
    bf* Xc = (bf*)(w + MD);
    bf* Wc[7];
    for (int i = 0; i < 7; ++i) Wc[i] = (bf*)(w + 2 * MD + i * WSZ);  // Wf = slots 6,7
    char* base2 = w + 2 * MD + 8 * WSZ;
    bf* Q  = (bf*)(base2);
    bf* K  = (bf*)(base2 + MD);
    bf* V  = (bf*)(base2 + 2 * MD);
    bf* O1 = (bf*)(base2 + 3 * MD);
    bf* Eb = (bf*)(base2 + 4 * MD);                     // S*S bf16 = 8.39 MB
    float* cs = (float*)(base2 + 4 * MD + (size_t)S * S * sizeof(bf));
    float* bias32[7];
    {
        char* bb = (char*)cs + (size_t)2 * B * S * sizeof(float);
        for (int i = 0; i < 7; ++i) bias32[i] = (float*)(bb + i * D * sizeof(float));
    }
    // aliases (verified against sequential stream order):
    bf* O2 = K;   // K[b] last read by scores_exp(b); O2[b] written after, by PV(b)
    bf* F1 = Q;   // Q dead after dir-2 score loop
    bf* F2 = V;   // V dead after dir-2 PV loop

    (void)hipMemsetAsync(cs, 0, (size_t)2 * B * S * sizeof(float), stream);

    dim3 blk(256);
    {
        int n = M * D;
        to_bf16<<<dim3((n + 1023) / 1024), blk, 0, stream>>>(d_in[0], Xs, n);
        to_bf16<<<dim3((n + 1023) / 1024), blk, 0, stream>>>(d_in[1], Xc, n);
        int nw = D * D;
        for (int i = 0; i < 6; ++i)
            to_bf16<<<dim3((nw + 1023) / 1024), blk, 0, stream>>>(Wsrc[i], Wc[i], nw);
        int nf = 2 * D * D;
        to_bf16<<<dim3((nf + 1023) / 1024), blk, 0, stream>>>(Wsrc[6], Wc[6], nf);
        for (int i = 0; i < 7; ++i)
            to_f32<<<dim3(3), blk, 0, stream>>>(bsrc[i], bias32[i], D);
    }

    dim3 gProj(M / BM, D / BN);      // 128 x 6
    dim3 gScore(S / BM, S / BN);     // 16 x 16 (per batch)
    dim3 gPV(S / BM, D / BN);        // 16 x 6  (per batch)
    const float rscale = 1.0f / sqrtf((float)D);
    const size_t SD = (size_t)S * D;

    // ---- direction 1: Q from self, K/V from conv ----
    gemm_nn<bf><<<gProj, blk, 0, stream>>>(Xs, Xs, NOSPLIT, Wc[0], bias32[0], Q, D, D, D, D);
    gemm_nn<bf><<<gProj, blk, 0, stream>>>(Xc, Xc, NOSPLIT, Wc[1], bias32[1], K, D, D, D, D);
    gemm_nn<bf><<<gProj, blk, 0, stream>>>(Xc, Xc, NOSPLIT, Wc[2], bias32[2], V, D, D, D, D);
    for (int b = 0; b < B; ++b) {
        float* csb = cs + (size_t)b * S;
        scores_exp<<<gScore, blk, 0, stream>>>(Q + b * SD, K + b * SD, Eb, csb, D, S, rscale);
        scale_rows<<<dim3(S), blk, 0, stream>>>(V + b * SD, csb, D);
        gemm_nn<bf><<<gPV, blk, 0, stream>>>(Eb, Eb, NOSPLIT, V + b * SD, nullptr, O1 + b * SD, S, S, D, D);
    }

    // ---- direction 2: Q from conv, K/V from self ----
    gemm_nn<bf><<<gProj, blk, 0, stream>>>(Xc, Xc, NOSPLIT, Wc[3], bias32[3], Q, D, D, D, D);
    gemm_nn<bf><<<gProj, blk, 0, stream>>>(Xs, Xs, NOSPLIT, Wc[4], bias32[4], K, D, D, D, D);
    gemm_nn<bf><<<gProj, blk, 0, stream>>>(Xs, Xs, NOSPLIT, Wc[5], bias32[5], V, D, D, D, D);
    for (int b = 0; b < B; ++b) {
        float* csb = cs + (size_t)(B + b) * S;
        scores_exp<<<gScore, blk, 0, stream>>>(Q + b * SD, K + b * SD, Eb, csb, D, S, rscale);
        scale_rows<<<dim3(S), blk, 0, stream>>>(V + b * SD, csb, D);
        gemm_nn<bf><<<gPV, blk, 0, stream>>>(Eb, Eb, NOSPLIT, V + b * SD, nullptr, O2 + b * SD, S, S, D, D);
    }

    // ---- gate + final split-A GEMM -> fp32 d_out ----
    gate_fuse<<<dim3(M), blk, 0, stream>>>(O1, O2, Xs, Xc, F1, F2, D);
    gemm_nn<float><<<gProj, blk, 0, stream>>>(F1, F2, D, Wc[6], bias32[6], out, 2 * D, D, D, D);
}

// Round 6
// 840.184 us; speedup vs baseline: 3.5415x; 3.5415x over previous
//
#include <hip/hip_runtime.h>
#include <hip/hip_bf16.h>

#define BM 128
#define BN 128
#define BK 32
#define LDSS 40   // LDS leading stride (elements): 80B rows, 16B-multiple, breaks pow2 banks

typedef short short8 __attribute__((ext_vector_type(8)));
typedef float f32x4 __attribute__((ext_vector_type(4)));

using bf = __hip_bfloat16;

static const int NOSPLIT = 1 << 30;

// ---------------------------------------------------------------------------
// fp32 -> bf16 cast, 4 elems/thread
// ---------------------------------------------------------------------------
__global__ __launch_bounds__(256)
void cast_bf16(const float* __restrict__ src, bf* __restrict__ dst, int n)
{
    int i = (blockIdx.x * 256 + threadIdx.x) * 4;
    if (i >= n) return;
    float4 v = *(const float4*)(src + i);
    bf o[4] = { __float2bfloat16(v.x), __float2bfloat16(v.y),
                __float2bfloat16(v.z), __float2bfloat16(v.w) };
    *(uint2*)(dst + i) = *(const uint2*)o;
}

// ---------------------------------------------------------------------------
// W [Kd][Nd] fp32 -> Wt [Nd][Kd] bf16 via 32x32 LDS tile (+1 pad)
// ---------------------------------------------------------------------------
__global__ __launch_bounds__(256)
void transpose_cast_w(const float* __restrict__ W, bf* __restrict__ Wt,
                      int Kd, int Nd)
{
    __shared__ float tile[32][33];
    int k0 = blockIdx.y * 32, n0 = blockIdx.x * 32;
    int t = threadIdx.x;
    int r = t >> 3, c = (t & 7) * 4;
    float4 v = *(const float4*)(W + (size_t)(k0 + r) * Nd + n0 + c);
    tile[r][c] = v.x; tile[r][c+1] = v.y; tile[r][c+2] = v.z; tile[r][c+3] = v.w;
    __syncthreads();
    bf o[4] = { __float2bfloat16(tile[c][r]),   __float2bfloat16(tile[c+1][r]),
                __float2bfloat16(tile[c+2][r]), __float2bfloat16(tile[c+3][r]) };
    *(uint2*)(Wt + (size_t)(n0 + r) * Kd + k0 + c) = *(const uint2*)o;
}

// ---------------------------------------------------------------------------
// C = A[M,K] @ Bt[N,K]^T + bias; bf16 in, fp32 acc. Both operands staged as
// contiguous rows -> conflict-free b128 LDS writes (no transpose scatter).
// TC: write C transposed (Ct[n][m], ldc = leading dim of Ct), 8B packed.
// Split-A at k=splitA into A2. z-batching via strides (elements).
// ---------------------------------------------------------------------------
template <typename CT, bool TC>
__global__ __launch_bounds__(256)
void gemm_nt(const bf* __restrict__ A, const bf* __restrict__ A2, int splitA, int lda,
             const bf* __restrict__ Bt, int ldb,
             const float* __restrict__ bias, CT* __restrict__ C, int ldc,
             int K, long long strA, long long strB, long long strC)
{
    __shared__ __align__(16) ushort sA[BM * LDSS];
    __shared__ __align__(16) ushort sB[BN * LDSS];

    const int z = blockIdx.z;
    A  += (long long)z * strA;
    A2 += (long long)z * strA;
    Bt += (long long)z * strB;
    C  += (long long)z * strC;

    const int t = threadIdx.x;
    const int m0 = blockIdx.x * BM;
    const int n0 = blockIdx.y * BN;
    const int wave = t >> 6, lane = t & 63;
    const int wm = wave >> 1, wn = wave & 1;
    const int lcol = lane & 15, quad = lane >> 4;

    const int sr = t >> 2;            // 0..63 staging row
    const int kg = (t & 3) << 3;      // 0,8,16,24

    f32x4 acc[4][4] = {};

    for (int kt = 0; kt < K; kt += BK) {
        const bf* Asrc = (kt < splitA) ? A : A2;
        const int ktt = (kt < splitA) ? kt : kt - splitA;
        *(uint4*)&sA[sr * LDSS + kg] =
            *(const uint4*)(Asrc + (size_t)(m0 + sr) * lda + ktt + kg);
        *(uint4*)&sA[(sr + 64) * LDSS + kg] =
            *(const uint4*)(Asrc + (size_t)(m0 + sr + 64) * lda + ktt + kg);
        *(uint4*)&sB[sr * LDSS + kg] =
            *(const uint4*)(Bt + (size_t)(n0 + sr) * ldb + kt + kg);
        *(uint4*)&sB[(sr + 64) * LDSS + kg] =
            *(const uint4*)(Bt + (size_t)(n0 + sr + 64) * ldb + kt + kg);
        __syncthreads();

        short8 af[4], bfr[4];
        #pragma unroll
        for (int i = 0; i < 4; ++i)
            af[i] = *(const short8*)&sA[(wm * 64 + i * 16 + lcol) * LDSS + quad * 8];
        #pragma unroll
        for (int j = 0; j < 4; ++j)
            bfr[j] = *(const short8*)&sB[(wn * 64 + j * 16 + lcol) * LDSS + quad * 8];
        #pragma unroll
        for (int i = 0; i < 4; ++i)
            #pragma unroll
            for (int j = 0; j < 4; ++j)
                acc[i][j] = __builtin_amdgcn_mfma_f32_16x16x32_bf16(af[i], bfr[j], acc[i][j], 0, 0, 0);
        __syncthreads();
    }

    #pragma unroll
    for (int j = 0; j < 4; ++j) {
        int col = n0 + wn * 64 + j * 16 + lcol;
        float bv = bias ? bias[col] : 0.0f;
        #pragma unroll
        for (int i = 0; i < 4; ++i) {
            int row = m0 + wm * 64 + i * 16 + quad * 4;
            if (!TC) {
                #pragma unroll
                for (int r4 = 0; r4 < 4; ++r4)
                    C[(size_t)(row + r4) * ldc + col] = (CT)(acc[i][j][r4] + bv);
            } else {
                bf o[4];
                #pragma unroll
                for (int r4 = 0; r4 < 4; ++r4)
                    o[r4] = __float2bfloat16(acc[i][j][r4] + bv);
                *(uint2*)((bf*)C + (size_t)col * ldc + row) = *(const uint2*)o;
            }
        }
    }
}

// ---------------------------------------------------------------------------
// E[q,k] = exp((Q[q,:].K[k,:]) * rscale) + colsum over q (softmax over QUERY
// axis). z-batched. Grid (S/BM, S/BN, cb). S = 2048 fixed.
// ---------------------------------------------------------------------------
__global__ __launch_bounds__(256)
void scores_exp(const bf* __restrict__ Q, const bf* __restrict__ Km,
                bf* __restrict__ E, float* __restrict__ colsum,
                int Dd, float rscale)
{
    const int S = 2048;
    __shared__ __align__(16) ushort sA[BM * LDSS];
    __shared__ __align__(16) ushort sB[BN * LDSS];

    const int z = blockIdx.z;
    Q  += (size_t)z * S * Dd;
    Km += (size_t)z * S * Dd;
    E  += (size_t)z * S * S;
    colsum += (size_t)z * S;

    const int t = threadIdx.x;
    const int m0 = blockIdx.x * BM;
    const int n0 = blockIdx.y * BN;
    const int wave = t >> 6, lane = t & 63;
    const int wm = wave >> 1, wn = wave & 1;
    const int lcol = lane & 15, quad = lane >> 4;
    const int sr = t >> 2;
    const int kg = (t & 3) << 3;

    f32x4 acc[4][4] = {};

    for (int kt = 0; kt < Dd; kt += BK) {
        *(uint4*)&sA[sr * LDSS + kg] =
            *(const uint4*)(Q + (size_t)(m0 + sr) * Dd + kt + kg);
        *(uint4*)&sA[(sr + 64) * LDSS + kg] =
            *(const uint4*)(Q + (size_t)(m0 + sr + 64) * Dd + kt + kg);
        *(uint4*)&sB[sr * LDSS + kg] =
            *(const uint4*)(Km + (size_t)(n0 + sr) * Dd + kt + kg);
        *(uint4*)&sB[(sr + 64) * LDSS + kg] =
            *(const uint4*)(Km + (size_t)(n0 + sr + 64) * Dd + kt + kg);
        __syncthreads();

        short8 af[4], bfr[4];
        #pragma unroll
        for (int i = 0; i < 4; ++i)
            af[i] = *(const short8*)&sA[(wm * 64 + i * 16 + lcol) * LDSS + quad * 8];
        #pragma unroll
        for (int j = 0; j < 4; ++j)
            bfr[j] = *(const short8*)&sB[(wn * 64 + j * 16 + lcol) * LDSS + quad * 8];
        #pragma unroll
        for (int i = 0; i < 4; ++i)
            #pragma unroll
            for (int j = 0; j < 4; ++j)
                acc[i][j] = __builtin_amdgcn_mfma_f32_16x16x32_bf16(af[i], bfr[j], acc[i][j], 0, 0, 0);
        __syncthreads();
    }

    #pragma unroll
    for (int j = 0; j < 4; ++j) {
        int col = n0 + wn * 64 + j * 16 + lcol;
        float csum = 0.f;
        #pragma unroll
        for (int i = 0; i < 4; ++i) {
            int row = m0 + wm * 64 + i * 16 + quad * 4;
            #pragma unroll
            for (int r4 = 0; r4 < 4; ++r4) {
                float e = __expf(acc[i][j][r4] * rscale);
                E[(size_t)(row + r4) * S + col] = __float2bfloat16(e);
                csum += e;
            }
        }
        csum += __shfl_xor(csum, 16);
        csum += __shfl_xor(csum, 32);
        if (quad == 0) atomicAdd(&colsum[col], csum);
    }
}

// Vt[d][col] /= cs[col], over a column window. Grid (ncols/1024, 768).
__global__ __launch_bounds__(256)
void scale_vt(bf* __restrict__ Vt, const float* __restrict__ cs, int ldv)
{
    int col = (blockIdx.x * 256 + threadIdx.x) * 4;
    bf* p = Vt + (size_t)blockIdx.y * ldv + col;
    bf v[4]; *(uint2*)v = *(const uint2*)p;
    float4 c4 = *(const float4*)(cs + col);
    v[0] = __float2bfloat16(__bfloat162float(v[0]) / c4.x);
    v[1] = __float2bfloat16(__bfloat162float(v[1]) / c4.y);
    v[2] = __float2bfloat16(__bfloat162float(v[2]) / c4.z);
    v[3] = __float2bfloat16(__bfloat162float(v[3]) / c4.w);
    *(uint2*)p = *(const uint2*)v;
}

// gating from fp32 originals: F1 = a2*sx+(1-a2)*cx ; F2 = a1*cx+(1-a1)*sx
__global__ __launch_bounds__(256)
void gate_fuse(const bf* __restrict__ O1, const bf* __restrict__ O2,
               const float* __restrict__ SX, const float* __restrict__ CX,
               bf* __restrict__ F1, bf* __restrict__ F2, int n)
{
    int i = (blockIdx.x * 256 + threadIdx.x) * 4;
    if (i >= n) return;
    bf o1[4], o2[4], f1[4], f2[4];
    *(uint2*)o1 = *(const uint2*)(O1 + i);
    *(uint2*)o2 = *(const uint2*)(O2 + i);
    float4 sx = *(const float4*)(SX + i);
    float4 cx = *(const float4*)(CX + i);
    #pragma unroll
    for (int e = 0; e < 4; ++e) {
        float s = (&sx.x)[e], c = (&cx.x)[e];
        float a1 = 1.0f / (1.0f + __expf(-tanhf(__bfloat162float(o1[e]))));
        float a2 = 1.0f / (1.0f + __expf(-tanhf(__bfloat162float(o2[e]))));
        f1[e] = __float2bfloat16(a2 * s + (1.0f - a2) * c);
        f2[e] = __float2bfloat16(a1 * c + (1.0f - a1) * s);
    }
    *(uint2*)(F1 + i) = *(const uint2*)f1;
    *(uint2*)(F2 + i) = *(const uint2*)f2;
}

extern "C" void kernel_launch(void* const* d_in, const int* in_sizes, int n_in,
                              void* d_out, int out_size, void* d_ws, size_t ws_size,
                              hipStream_t stream)
{
    const int B = 8, S = 2048, D = 768;
    const int M = B * S;                        // 16384

    const float* SX = (const float*)d_in[0];
    const float* CX = (const float*)d_in[1];
    const float* Wsrc[7] = { (const float*)d_in[2],  (const float*)d_in[4],
                             (const float*)d_in[6],  (const float*)d_in[8],
                             (const float*)d_in[10], (const float*)d_in[12],
                             (const float*)d_in[14] };
    const float* bias[7] = { (const float*)d_in[3],  (const float*)d_in[5],
                             (const float*)d_in[7],  (const float*)d_in[9],
                             (const float*)d_in[11], (const float*)d_in[13],
                             (const float*)d_in[15] };
    float* out = (float*)d_out;

    // ---- workspace layout: fixed 160.6 MB + adaptive E chunk ----
    char* w = (char*)d_ws;
    const size_t MD  = (size_t)M * D * sizeof(bf);       // 25.17 MB
    const size_t WSZ = (size_t)D * D * sizeof(bf);       // 1.18 MB
    const size_t SSB = (size_t)S * S * sizeof(bf);       // 8.39 MB per E batch
    bf* Xs = (bf*)(w);
    bf* Xc = (bf*)(w + MD);
    bf* Wt[7];
    for (int i = 0; i < 7; ++i) Wt[i] = (bf*)(w + 2 * MD + i * WSZ);  // Wtf = slots 6,7
    char* base2 = w + 2 * MD + 8 * WSZ;
    bf* Q  = (bf*)(base2);
    bf* Kb = (bf*)(base2 + MD);
    bf* Vt = (bf*)(base2 + 2 * MD);
    bf* O1 = (bf*)(base2 + 3 * MD);
    float* cs = (float*)(base2 + 4 * MD);                // 2*B*S fp32 = 128 KB
    char* Eb0 = base2 + 4 * MD + (size_t)2 * B * S * sizeof(float);
    bf* E = (bf*)Eb0;
    // adaptive chunk: how many batches of E fit in remaining workspace
    int cb;
    {
        size_t fixed = (size_t)(Eb0 - w);
        size_t avail = ws_size > fixed ? ws_size - fixed : SSB;
        long long c = (long long)(avail / SSB);
        cb = c < 1 ? 1 : (c > 8 ? 8 : (int)c);
    }
    // aliases (stream-order verified): O2=Xs (dead after dir-2 projections);
    // F1=Kb, F2=Vt (dead after dir-2 scores / dir-2 PV).
    bf* O2 = Xs;
    bf* F1 = Kb;
    bf* F2 = Vt;

    (void)hipMemsetAsync(cs, 0, (size_t)2 * B * S * sizeof(float), stream);

    dim3 blk(256);
    // ---- casts + weight transposes ----
    {
        int n = M * D;
        cast_bf16<<<dim3(n / 1024), blk, 0, stream>>>(SX, Xs, n);
        cast_bf16<<<dim3(n / 1024), blk, 0, stream>>>(CX, Xc, n);
        for (int i = 0; i < 6; ++i)
            transpose_cast_w<<<dim3(D / 32, D / 32), blk, 0, stream>>>(Wsrc[i], Wt[i], D, D);
        transpose_cast_w<<<dim3(D / 32, 2 * D / 32), blk, 0, stream>>>(Wsrc[6], Wt[6], 2 * D, D);
    }

    dim3 gProj(M / BM, D / BN);      // 128 x 6
    const float rscale = 1.0f / sqrtf((float)D);
    const size_t SD = (size_t)S * D;
    const long long SS = (long long)S * S;

    for (int dir = 0; dir < 2; ++dir) {
        const bf* Xq = dir == 0 ? Xs : Xc;   // queries source
        const bf* Xk = dir == 0 ? Xc : Xs;   // keys/values source
        bf* Wq = Wt[dir * 3 + 0];
        bf* Wk = Wt[dir * 3 + 1];
        bf* Wv = Wt[dir * 3 + 2];
        const float* bq = bias[dir * 3 + 0];
        const float* bk = bias[dir * 3 + 1];
        const float* bv = bias[dir * 3 + 2];
        bf* O = dir == 0 ? O1 : O2;
        float* csd = cs + (size_t)dir * B * S;

        gemm_nt<bf, false><<<gProj, blk, 0, stream>>>(Xq, Xq, NOSPLIT, D, Wq, D, bq, Q,  D, D, 0, 0, 0);
        gemm_nt<bf, false><<<gProj, blk, 0, stream>>>(Xk, Xk, NOSPLIT, D, Wk, D, bk, Kb, D, D, 0, 0, 0);
        gemm_nt<bf, true ><<<gProj, blk, 0, stream>>>(Xk, Xk, NOSPLIT, D, Wv, D, bv, Vt, M, D, 0, 0, 0);

        for (int c0 = 0; c0 < B; c0 += cb) {
            int cbc = (B - c0 < cb) ? (B - c0) : cb;
            scores_exp<<<dim3(S / BM, S / BN, cbc), blk, 0, stream>>>(
                Q + c0 * SD, Kb + c0 * SD, E, csd + (size_t)c0 * S, D, rscale);
            scale_vt<<<dim3(cbc * S / 1024, D), blk, 0, stream>>>(
                Vt + (size_t)c0 * S, csd + (size_t)c0 * S, M);
            gemm_nt<bf, false><<<dim3(S / BM, D / BN, cbc), blk, 0, stream>>>(
                E, E, NOSPLIT, S, Vt + (size_t)c0 * S, M, nullptr,
                O + c0 * SD, D, S, SS, S, (long long)SD);
        }
    }

    // ---- gate (fp32 originals) + final split-A GEMM -> fp32 out ----
    gate_fuse<<<dim3(M * D / 1024), blk, 0, stream>>>(O1, O2, SX, CX, F1, F2, M * D);
    gemm_nt<float, false><<<gProj, blk, 0, stream>>>(F1, F2, D, D, Wt[6], 2 * D,
                                                     bias[6], out, D, 2 * D, 0, 0, 0);
}

// Round 7
// 809.034 us; speedup vs baseline: 3.6778x; 1.0385x over previous
//
#include <hip/hip_runtime.h>
#include <hip/hip_bf16.h>

#define BM 128
#define BN 128
#define BK 32   // 32 bf16 = 64B per LDS row, unpadded (global_load_lds-compatible)

typedef short short8 __attribute__((ext_vector_type(8)));
typedef float f32x4 __attribute__((ext_vector_type(4)));

using bf = __hip_bfloat16;

static const int NOSPLIT = 1 << 30;

// ---------------------------------------------------------------------------
// async 16B global -> LDS (direct DMA, no VGPR round-trip).
// HW semantics: per-lane dest = wave-uniform lds base + lane*16B.
// ---------------------------------------------------------------------------
__device__ __forceinline__ void gld16(const void* g, void* l)
{
    __builtin_amdgcn_global_load_lds(
        (__attribute__((address_space(1))) void*)g,
        (__attribute__((address_space(3))) void*)l, 16, 0, 0);
}

// LDS offset (ushorts) of k-group kg8 (8 bf16) of row `row` under the XOR
// swizzle. Swizzle keeps DMA lane order contiguous AND spreads ds_read_b128
// start banks (2-way aliasing only = free).
__device__ __forceinline__ int lofs(int row, int kg8)
{
    return row * 32 + ((kg8 ^ ((row >> 1) & 3)) << 3);
}

// ---------------------------------------------------------------------------
// fp32 -> bf16 cast, 4 elems/thread
// ---------------------------------------------------------------------------
__global__ __launch_bounds__(256)
void cast_bf16(const float* __restrict__ src, bf* __restrict__ dst, int n)
{
    int i = (blockIdx.x * 256 + threadIdx.x) * 4;
    if (i >= n) return;
    float4 v = *(const float4*)(src + i);
    bf o[4] = { __float2bfloat16(v.x), __float2bfloat16(v.y),
                __float2bfloat16(v.z), __float2bfloat16(v.w) };
    *(uint2*)(dst + i) = *(const uint2*)o;
}

// ---------------------------------------------------------------------------
// W [Kd][Nd] fp32 -> Wt [Nd][Kd] bf16 via 32x32 LDS tile (+1 pad)
// ---------------------------------------------------------------------------
__global__ __launch_bounds__(256)
void transpose_cast_w(const float* __restrict__ W, bf* __restrict__ Wt,
                      int Kd, int Nd)
{
    __shared__ float tile[32][33];
    int k0 = blockIdx.y * 32, n0 = blockIdx.x * 32;
    int t = threadIdx.x;
    int r = t >> 3, c = (t & 7) * 4;
    float4 v = *(const float4*)(W + (size_t)(k0 + r) * Nd + n0 + c);
    tile[r][c] = v.x; tile[r][c+1] = v.y; tile[r][c+2] = v.z; tile[r][c+3] = v.w;
    __syncthreads();
    bf o[4] = { __float2bfloat16(tile[c][r]),   __float2bfloat16(tile[c+1][r]),
                __float2bfloat16(tile[c+2][r]), __float2bfloat16(tile[c+3][r]) };
    *(uint2*)(Wt + (size_t)(n0 + r) * Kd + k0 + c) = *(const uint2*)o;
}

// ---------------------------------------------------------------------------
// C = A[M,K] @ Bt[N,K]^T + bias; bf16 in, fp32 acc. Staging via async
// global_load_lds_dwordx4 into the swizzled unpadded tile.
// TC: write C transposed (Ct[n][m], 8B packed). Split-A at k=splitA.
// ---------------------------------------------------------------------------
template <typename CT, bool TC>
__global__ __launch_bounds__(256)
void gemm_nt(const bf* __restrict__ A, const bf* __restrict__ A2, int splitA, int lda,
             const bf* __restrict__ Bt, int ldb,
             const float* __restrict__ bias, CT* __restrict__ C, int ldc,
             int K, long long strA, long long strB, long long strC)
{
    __shared__ __align__(16) ushort sA[BM * 32];   // 8 KB, unpadded
    __shared__ __align__(16) ushort sB[BN * 32];

    const int z = blockIdx.z;
    A  += (long long)z * strA;
    A2 += (long long)z * strA;
    Bt += (long long)z * strB;
    C  += (long long)z * strC;

    const int t = threadIdx.x;
    const int m0 = blockIdx.x * BM;
    const int n0 = blockIdx.y * BN;
    const int wave = t >> 6, lane = t & 63;
    const int wm = wave >> 1, wn = wave & 1;
    const int lcol = lane & 15, quad = lane >> 4;
    const int rl = lane >> 2, cslot = lane & 3;    // staging: 16 rows x 4 16B-slots

    f32x4 acc[4][4] = {};

    for (int kt = 0; kt < K; kt += BK) {
        const bf* Asrc = (kt < splitA) ? A : A2;
        const int ktt = (kt < splitA) ? kt : kt - splitA;
        #pragma unroll
        for (int it = 0; it < 2; ++it) {
            int br  = wave * 16 + it * 64;          // wave-uniform base row
            int row = br + rl;
            int kg  = cslot ^ ((row >> 1) & 3);     // source-side swizzle
            gld16(Asrc + (size_t)(m0 + row) * lda + ktt + kg * 8, &sA[br * 32]);
            gld16(Bt   + (size_t)(n0 + row) * ldb + kt  + kg * 8, &sB[br * 32]);
        }
        __syncthreads();   // drains vmcnt (async DMA) + joins waves

        short8 af[4], bfr[4];
        #pragma unroll
        for (int i = 0; i < 4; ++i)
            af[i] = *(const short8*)&sA[lofs(wm * 64 + i * 16 + lcol, quad)];
        #pragma unroll
        for (int j = 0; j < 4; ++j)
            bfr[j] = *(const short8*)&sB[lofs(wn * 64 + j * 16 + lcol, quad)];
        #pragma unroll
        for (int i = 0; i < 4; ++i)
            #pragma unroll
            for (int j = 0; j < 4; ++j)
                acc[i][j] = __builtin_amdgcn_mfma_f32_16x16x32_bf16(af[i], bfr[j], acc[i][j], 0, 0, 0);
        __syncthreads();
    }

    #pragma unroll
    for (int j = 0; j < 4; ++j) {
        int col = n0 + wn * 64 + j * 16 + lcol;
        float bv = bias ? bias[col] : 0.0f;
        #pragma unroll
        for (int i = 0; i < 4; ++i) {
            int row = m0 + wm * 64 + i * 16 + quad * 4;
            if (!TC) {
                #pragma unroll
                for (int r4 = 0; r4 < 4; ++r4)
                    C[(size_t)(row + r4) * ldc + col] = (CT)(acc[i][j][r4] + bv);
            } else {
                bf o[4];
                #pragma unroll
                for (int r4 = 0; r4 < 4; ++r4)
                    o[r4] = __float2bfloat16(acc[i][j][r4] + bv);
                *(uint2*)((bf*)C + (size_t)col * ldc + row) = *(const uint2*)o;
            }
        }
    }
}

// ---------------------------------------------------------------------------
// E[q,k] = exp((Q[q,:].K[k,:]) * rscale) + colsum over q (softmax over QUERY
// axis). z-batched. Grid (S/BM, S/BN, cb). S = 2048 fixed.
// ---------------------------------------------------------------------------
__global__ __launch_bounds__(256)
void scores_exp(const bf* __restrict__ Q, const bf* __restrict__ Km,
                bf* __restrict__ E, float* __restrict__ colsum,
                int Dd, float rscale)
{
    const int S = 2048;
    __shared__ __align__(16) ushort sA[BM * 32];
    __shared__ __align__(16) ushort sB[BN * 32];

    const int z = blockIdx.z;
    Q  += (size_t)z * S * Dd;
    Km += (size_t)z * S * Dd;
    E  += (size_t)z * S * S;
    colsum += (size_t)z * S;

    const int t = threadIdx.x;
    const int m0 = blockIdx.x * BM;
    const int n0 = blockIdx.y * BN;
    const int wave = t >> 6, lane = t & 63;
    const int wm = wave >> 1, wn = wave & 1;
    const int lcol = lane & 15, quad = lane >> 4;
    const int rl = lane >> 2, cslot = lane & 3;

    f32x4 acc[4][4] = {};

    for (int kt = 0; kt < Dd; kt += BK) {
        #pragma unroll
        for (int it = 0; it < 2; ++it) {
            int br  = wave * 16 + it * 64;
            int row = br + rl;
            int kg  = cslot ^ ((row >> 1) & 3);
            gld16(Q  + (size_t)(m0 + row) * Dd + kt + kg * 8, &sA[br * 32]);
            gld16(Km + (size_t)(n0 + row) * Dd + kt + kg * 8, &sB[br * 32]);
        }
        __syncthreads();

        short8 af[4], bfr[4];
        #pragma unroll
        for (int i = 0; i < 4; ++i)
            af[i] = *(const short8*)&sA[lofs(wm * 64 + i * 16 + lcol, quad)];
        #pragma unroll
        for (int j = 0; j < 4; ++j)
            bfr[j] = *(const short8*)&sB[lofs(wn * 64 + j * 16 + lcol, quad)];
        #pragma unroll
        for (int i = 0; i < 4; ++i)
            #pragma unroll
            for (int j = 0; j < 4; ++j)
                acc[i][j] = __builtin_amdgcn_mfma_f32_16x16x32_bf16(af[i], bfr[j], acc[i][j], 0, 0, 0);
        __syncthreads();
    }

    #pragma unroll
    for (int j = 0; j < 4; ++j) {
        int col = n0 + wn * 64 + j * 16 + lcol;
        float csum = 0.f;
        #pragma unroll
        for (int i = 0; i < 4; ++i) {
            int row = m0 + wm * 64 + i * 16 + quad * 4;
            #pragma unroll
            for (int r4 = 0; r4 < 4; ++r4) {
                float e = __expf(acc[i][j][r4] * rscale);
                E[(size_t)(row + r4) * S + col] = __float2bfloat16(e);
                csum += e;
            }
        }
        csum += __shfl_xor(csum, 16);
        csum += __shfl_xor(csum, 32);
        if (quad == 0) atomicAdd(&colsum[col], csum);
    }
}

// Vt[d][col] /= cs[col], over a column window. Grid (ncols/1024, 768).
__global__ __launch_bounds__(256)
void scale_vt(bf* __restrict__ Vt, const float* __restrict__ cs, int ldv)
{
    int col = (blockIdx.x * 256 + threadIdx.x) * 4;
    bf* p = Vt + (size_t)blockIdx.y * ldv + col;
    bf v[4]; *(uint2*)v = *(const uint2*)p;
    float4 c4 = *(const float4*)(cs + col);
    v[0] = __float2bfloat16(__bfloat162float(v[0]) / c4.x);
    v[1] = __float2bfloat16(__bfloat162float(v[1]) / c4.y);
    v[2] = __float2bfloat16(__bfloat162float(v[2]) / c4.z);
    v[3] = __float2bfloat16(__bfloat162float(v[3]) / c4.w);
    *(uint2*)p = *(const uint2*)v;
}

// gating from fp32 originals: F1 = a2*sx+(1-a2)*cx ; F2 = a1*cx+(1-a1)*sx
__global__ __launch_bounds__(256)
void gate_fuse(const bf* __restrict__ O1, const bf* __restrict__ O2,
               const float* __restrict__ SX, const float* __restrict__ CX,
               bf* __restrict__ F1, bf* __restrict__ F2, int n)
{
    int i = (blockIdx.x * 256 + threadIdx.x) * 4;
    if (i >= n) return;
    bf o1[4], o2[4], f1[4], f2[4];
    *(uint2*)o1 = *(const uint2*)(O1 + i);
    *(uint2*)o2 = *(const uint2*)(O2 + i);
    float4 sx = *(const float4*)(SX + i);
    float4 cx = *(const float4*)(CX + i);
    #pragma unroll
    for (int e = 0; e < 4; ++e) {
        float s = (&sx.x)[e], c = (&cx.x)[e];
        float a1 = 1.0f / (1.0f + __expf(-tanhf(__bfloat162float(o1[e]))));
        float a2 = 1.0f / (1.0f + __expf(-tanhf(__bfloat162float(o2[e]))));
        f1[e] = __float2bfloat16(a2 * s + (1.0f - a2) * c);
        f2[e] = __float2bfloat16(a1 * c + (1.0f - a1) * s);
    }
    *(uint2*)(F1 + i) = *(const uint2*)f1;
    *(uint2*)(F2 + i) = *(const uint2*)f2;
}

extern "C" void kernel_launch(void* const* d_in, const int* in_sizes, int n_in,
                              void* d_out, int out_size, void* d_ws, size_t ws_size,
                              hipStream_t stream)
{
    const int B = 8, S = 2048, D = 768;
    const int M = B * S;                        // 16384

    const float* SX = (const float*)d_in[0];
    const float* CX = (const float*)d_in[1];
    const float* Wsrc[7] = { (const float*)d_in[2],  (const float*)d_in[4],
                             (const float*)d_in[6],  (const float*)d_in[8],
                             (const float*)d_in[10], (const float*)d_in[12],
                             (const float*)d_in[14] };
    const float* bias[7] = { (const float*)d_in[3],  (const float*)d_in[5],
                             (const float*)d_in[7],  (const float*)d_in[9],
                             (const float*)d_in[11], (const float*)d_in[13],
                             (const float*)d_in[15] };
    float* out = (float*)d_out;

    // ---- workspace layout: fixed 160.6 MB + adaptive E chunk ----
    char* w = (char*)d_ws;
    const size_t MD  = (size_t)M * D * sizeof(bf);       // 25.17 MB
    const size_t WSZ = (size_t)D * D * sizeof(bf);       // 1.18 MB
    const size_t SSB = (size_t)S * S * sizeof(bf);       // 8.39 MB per E batch
    bf* Xs = (bf*)(w);
    bf* Xc = (bf*)(w + MD);
    bf* Wt[7];
    for (int i = 0; i < 7; ++i) Wt[i] = (bf*)(w + 2 * MD + i * WSZ);  // Wtf = slots 6,7
    char* base2 = w + 2 * MD + 8 * WSZ;
    bf* Q  = (bf*)(base2);
    bf* Kb = (bf*)(base2 + MD);
    bf* Vt = (bf*)(base2 + 2 * MD);
    bf* O1 = (bf*)(base2 + 3 * MD);
    float* cs = (float*)(base2 + 4 * MD);                // 2*B*S fp32 = 128 KB
    char* Eb0 = base2 + 4 * MD + (size_t)2 * B * S * sizeof(float);
    bf* E = (bf*)Eb0;
    int cb;
    {
        size_t fixed = (size_t)(Eb0 - w);
        size_t avail = ws_size > fixed ? ws_size - fixed : SSB;
        long long c = (long long)(avail / SSB);
        cb = c < 1 ? 1 : (c > 8 ? 8 : (int)c);
    }
    // aliases (stream-order verified in r6, which passed):
    bf* O2 = Xs;
    bf* F1 = Kb;
    bf* F2 = Vt;

    (void)hipMemsetAsync(cs, 0, (size_t)2 * B * S * sizeof(float), stream);

    dim3 blk(256);
    {
        int n = M * D;
        cast_bf16<<<dim3(n / 1024), blk, 0, stream>>>(SX, Xs, n);
        cast_bf16<<<dim3(n / 1024), blk, 0, stream>>>(CX, Xc, n);
        for (int i = 0; i < 6; ++i)
            transpose_cast_w<<<dim3(D / 32, D / 32), blk, 0, stream>>>(Wsrc[i], Wt[i], D, D);
        transpose_cast_w<<<dim3(D / 32, 2 * D / 32), blk, 0, stream>>>(Wsrc[6], Wt[6], 2 * D, D);
    }

    dim3 gProj(M / BM, D / BN);      // 128 x 6
    const float rscale = 1.0f / sqrtf((float)D);
    const size_t SD = (size_t)S * D;
    const long long SS = (long long)S * S;

    for (int dir = 0; dir < 2; ++dir) {
        const bf* Xq = dir == 0 ? Xs : Xc;   // queries source
        const bf* Xk = dir == 0 ? Xc : Xs;   // keys/values source
        bf* Wq = Wt[dir * 3 + 0];
        bf* Wk = Wt[dir * 3 + 1];
        bf* Wv = Wt[dir * 3 + 2];
        const float* bq = bias[dir * 3 + 0];
        const float* bk = bias[dir * 3 + 1];
        const float* bv = bias[dir * 3 + 2];
        bf* O = dir == 0 ? O1 : O2;
        float* csd = cs + (size_t)dir * B * S;

        gemm_nt<bf, false><<<gProj, blk, 0, stream>>>(Xq, Xq, NOSPLIT, D, Wq, D, bq, Q,  D, D, 0, 0, 0);
        gemm_nt<bf, false><<<gProj, blk, 0, stream>>>(Xk, Xk, NOSPLIT, D, Wk, D, bk, Kb, D, D, 0, 0, 0);
        gemm_nt<bf, true ><<<gProj, blk, 0, stream>>>(Xk, Xk, NOSPLIT, D, Wv, D, bv, Vt, M, D, 0, 0, 0);

        for (int c0 = 0; c0 < B; c0 += cb) {
            int cbc = (B - c0 < cb) ? (B - c0) : cb;
            scores_exp<<<dim3(S / BM, S / BN, cbc), blk, 0, stream>>>(
                Q + c0 * SD, Kb + c0 * SD, E, csd + (size_t)c0 * S, D, rscale);
            scale_vt<<<dim3(cbc * S / 1024, D), blk, 0, stream>>>(
                Vt + (size_t)c0 * S, csd + (size_t)c0 * S, M);
            gemm_nt<bf, false><<<dim3(S / BM, D / BN, cbc), blk, 0, stream>>>(
                E, E, NOSPLIT, S, Vt + (size_t)c0 * S, M, nullptr,
                O + c0 * SD, D, S, SS, S, (long long)SD);
        }
    }

    // ---- gate (fp32 originals) + final split-A GEMM -> fp32 out ----
    gate_fuse<<<dim3(M * D / 1024), blk, 0, stream>>>(O1, O2, SX, CX, F1, F2, M * D);
    gemm_nt<float, false><<<gProj, blk, 0, stream>>>(F1, F2, D, D, Wt[6], 2 * D,
                                                     bias[6], out, D, 2 * D, 0, 0, 0);
}